// Round 3
// baseline (65.055 us; speedup 1.0000x reference)
//
#include <hip/hip_runtime.h>

#define EPSF 1e-6f

// K1: one 64-lane wave per (b,c) plane. Lane = (g = lane>>3, c = lane&7);
// iteration t covers row 8t+g, cols [4c, 4c+4).
// Phase 1 (per-lane): band maxes m0..m3, boundary row-bands z2a/z2b, edge
// columns E1/E2. Phase 2: g-bit butterfly (xor 8,16,32) -> per-chunk values.
// Phase 3: c-bit windowed butterflies -> the 14 region maxes, stored
// rm[p*16 + r]; per-block sum-of-squares atomically added into ssp[b*16+r].
__global__ __launch_bounds__(256) void k1_regions(
    const float* __restrict__ x, float* __restrict__ rm,
    float* __restrict__ ssp) {
  const int lane = threadIdx.x & 63;
  const int wv = threadIdx.x >> 6;
  const int p = blockIdx.x * 4 + wv;  // plane index, 0..65535
  const float4* xp = reinterpret_cast<const float4*>(x) + (size_t)p * 256;

  const int c = lane & 7;
  const int g = lane >> 3;
  const bool c5 = (c == 5), c2 = (c == 2);
  const bool eact = c5 || c2;
  const bool glt5 = (g < 5), gge3 = (g >= 3);

  float m[4], e[4];
#pragma unroll
  for (int t = 0; t < 4; ++t) {
    const float4 v = xp[t * 64 + lane];
    m[t] = fmaxf(fmaxf(v.x, v.y), fmaxf(v.z, v.w));
    const float ev = c5 ? v.x : v.w;  // col 20 (chunk5) / col 11 (chunk2)
    e[t] = eact ? ev : -INFINITY;
  }

  float vals[8];
  vals[0] = m[0];
  vals[1] = m[1];
  vals[2] = m[2];
  vals[3] = m[3];
  vals[4] = glt5 ? m[2] : -INFINITY;                            // rows 16..20
  vals[5] = gge3 ? m[1] : -INFINITY;                            // rows 11..15
  vals[6] = fmaxf(fmaxf(e[0], e[1]), glt5 ? e[2] : -INFINITY);  // rows [0,21)
  vals[7] = fmaxf(fmaxf(e[2], e[3]), gge3 ? e[1] : -INFINITY);  // rows [11,32)

  // g-bit allreduce (bits 8,16,32): every lane gets its chunk's 8 values.
#pragma unroll
  for (int off = 8; off <= 32; off <<= 1) {
#pragma unroll
    for (int i = 0; i < 8; ++i)
      vals[i] = fmaxf(vals[i], __shfl_xor(vals[i], off, 64));
  }

  // Per-chunk row-band composites.
  const float M2a = fmaxf(fmaxf(vals[0], vals[1]), vals[4]);  // rows [0,21)
  const float M2b = fmaxf(vals[5], fmaxf(vals[2], vals[3]));  // rows [11,32)
  const float M3a = fmaxf(vals[0], vals[1]);                  // rows [0,16)
  const float M3b = fmaxf(vals[1], vals[2]);                  // rows [8,24)
  const float M3c = fmaxf(vals[2], vals[3]);                  // rows [16,32)
  const float E1 = vals[6], E2 = vals[7];

  // Scale-2 regions: masked full butterflies over c bits.
  float a1 = (c <= 4) ? M2a : (c5 ? E1 : -INFINITY);  // cols [0,21)
  float a2 = (c >= 3) ? M2a : (c2 ? E1 : -INFINITY);  // cols [11,32)
  float a3 = (c <= 4) ? M2b : (c5 ? E2 : -INFINITY);
  float a4 = (c >= 3) ? M2b : (c2 ? E2 : -INFINITY);
#pragma unroll
  for (int off = 1; off <= 4; off <<= 1) {
    a1 = fmaxf(a1, __shfl_xor(a1, off, 64));
    a2 = fmaxf(a2, __shfl_xor(a2, off, 64));
    a3 = fmaxf(a3, __shfl_xor(a3, off, 64));
    a4 = fmaxf(a4, __shfl_xor(a4, off, 64));
  }

  // Scale-3: pair (xor1) -> quad (xor2) + mid (xor6: pair23<->pair45).
  const float pA = fmaxf(M3a, __shfl_xor(M3a, 1, 64));
  const float pB = fmaxf(M3b, __shfl_xor(M3b, 1, 64));
  const float pC = fmaxf(M3c, __shfl_xor(M3c, 1, 64));
  const float qA = fmaxf(pA, __shfl_xor(pA, 2, 64));
  const float qB = fmaxf(pB, __shfl_xor(pB, 2, 64));
  const float qC = fmaxf(pC, __shfl_xor(pC, 2, 64));
  const float mA = fmaxf(pA, __shfl_xor(pA, 6, 64));  // valid lanes c=2..5
  const float mB = fmaxf(pB, __shfl_xor(pB, 6, 64));
  const float mC = fmaxf(pC, __shfl_xor(pC, 6, 64));

  // Global region: max over both quads of (rows[0,16) U rows[16,32)).
  const float t0 = fmaxf(qA, qC);
  const float r0 = fmaxf(t0, __shfl_xor(t0, 4, 64));

  // Gather values not locally present at their destination lane.
  const float b5 = __shfl(qA, 0, 64);   // M3a quad0 for lane 5
  const float b6 = __shfl(mA, 2, 64);   // M3a mid   for lane 6
  const float b9 = __shfl(mB, 2, 64);   // M3b mid   for lane 9
  const float b10 = __shfl(qB, 4, 64);  // M3b quad1 for lane 10

  // Destination lane l holds region r_l:
  //  0:r0  1..4:a1..a4  5:3a-q0  6:3a-mid  7:3a-q1(c7 local)
  //  8:3b-q0(c0 local)  9:3b-mid  10:3b-q1  11:3c-q0(c3)  12:3c-mid(c4)
  //  13:3c-q1(c5)
  float outv = r0;
  outv = (lane == 1) ? a1 : outv;
  outv = (lane == 2) ? a2 : outv;
  outv = (lane == 3) ? a3 : outv;
  outv = (lane == 4) ? a4 : outv;
  outv = (lane == 5) ? b5 : outv;
  outv = (lane == 6) ? b6 : outv;
  outv = (lane == 7) ? qA : outv;
  outv = (lane == 8) ? qB : outv;
  outv = (lane == 9) ? b9 : outv;
  outv = (lane == 10) ? b10 : outv;
  outv = (lane == 11) ? qC : outv;
  outv = (lane == 12) ? mC : outv;
  outv = (lane == 13) ? qC : outv;

  if (lane < 14) rm[(size_t)p * 16 + lane] = outv;

  // Per-block SS partial -> one atomicAdd set per block (14 per block).
  __shared__ float red[4][16];
  if (lane < 14) red[wv][lane] = outv * outv;
  __syncthreads();
  if (wv == 0 && lane < 14) {
    const int b = (blockIdx.x * 4) >> 11;
    atomicAdd(&ssp[b * 16 + lane],
              red[0][lane] + red[1][lane] + red[2][lane] + red[3][lane]);
  }
}

// K2: 256 blocks (b = bid>>3, slice = bid&7): build ninv[14] from ssp, apply.
__global__ __launch_bounds__(256) void k2_apply(
    const float* __restrict__ rm, const float* __restrict__ ssp,
    float* __restrict__ out) {
  const int bid = blockIdx.x;
  const int tid = threadIdx.x;
  const int b = bid >> 3;
  __shared__ float ninv[14];
  if (tid < 14) {
    const float s = ssp[b * 16 + tid];
    const float w = (tid == 0) ? 2.0f : 1.0f;  // global region == l=1 region
    ninv[tid] = w / (sqrtf(s) + EPSF);
  }
  __syncthreads();
  const int p = b * 2048 + (bid & 7) * 256 + tid;
  const float4* q = reinterpret_cast<const float4*>(rm) + (size_t)p * 4;
  const float4 q0 = q[0], q1 = q[1], q2 = q[2], q3 = q[3];
  float o = ninv[0] * q0.x + ninv[1] * q0.y + ninv[2] * q0.z + ninv[3] * q0.w;
  o += ninv[4] * q1.x + ninv[5] * q1.y + ninv[6] * q1.z + ninv[7] * q1.w;
  o += ninv[8] * q2.x + ninv[9] * q2.y + ninv[10] * q2.z + ninv[11] * q2.w;
  o += ninv[12] * q3.x + ninv[13] * q3.y;
  out[p] = o;
}

extern "C" void kernel_launch(void* const* d_in, const int* in_sizes, int n_in,
                              void* d_out, int out_size, void* d_ws, size_t ws_size,
                              hipStream_t stream) {
  const float* x = (const float*)d_in[0];
  float* out = (float*)d_out;

  const size_t RM_BYTES = (size_t)65536 * 16 * 4;  // 4.19 MB
  float* rm = (float*)d_ws;
  float* ssp = (float*)((char*)d_ws + RM_BYTES);   // 32*16 floats

  hipMemsetAsync(ssp, 0, 32 * 16 * sizeof(float), stream);
  k1_regions<<<16384, 256, 0, stream>>>(x, rm, ssp);
  k2_apply<<<256, 256, 0, stream>>>(rm, ssp, out);
}

// Round 4
// 49.979 us; speedup vs baseline: 1.3016x; 1.3016x over previous
//
#include <hip/hip_runtime.h>

#define EPSF 1e-6f

// K1: one 64-lane wave per (b,c) plane. Lane = (g = lane>>3, c = lane&7);
// iteration t covers row 8t+g, cols [4c, 4c+4).
// Phase 1 (per-lane): band maxes m0..m3, boundary row-bands z2a/z2b, edge
// columns E1/E2. Phase 2: g-bit butterfly (xor 8,16,32) -> per-chunk values.
// Phase 3: c-bit windowed butterflies -> 14 region maxes -> rm[p*16 + r].
// Per-block sum-of-squares partial -> sspart[bid*16 + r] (plain stores,
// no atomics: round-3's 229k atomics onto 32 cache lines serialized at the
// coherence point and cost ~10us).
__global__ __launch_bounds__(256) void k1_regions(
    const float* __restrict__ x, float* __restrict__ rm,
    float* __restrict__ sspart) {
  const int lane = threadIdx.x & 63;
  const int wv = threadIdx.x >> 6;
  const int p = blockIdx.x * 4 + wv;  // plane index, 0..65535
  const float4* xp = reinterpret_cast<const float4*>(x) + (size_t)p * 256;

  const int c = lane & 7;
  const int g = lane >> 3;
  const bool c5 = (c == 5), c2 = (c == 2);
  const bool eact = c5 || c2;
  const bool glt5 = (g < 5), gge3 = (g >= 3);

  float m[4], e[4];
#pragma unroll
  for (int t = 0; t < 4; ++t) {
    const float4 v = xp[t * 64 + lane];
    m[t] = fmaxf(fmaxf(v.x, v.y), fmaxf(v.z, v.w));
    const float ev = c5 ? v.x : v.w;  // col 20 (chunk5) / col 11 (chunk2)
    e[t] = eact ? ev : -INFINITY;
  }

  float vals[8];
  vals[0] = m[0];
  vals[1] = m[1];
  vals[2] = m[2];
  vals[3] = m[3];
  vals[4] = glt5 ? m[2] : -INFINITY;                            // rows 16..20
  vals[5] = gge3 ? m[1] : -INFINITY;                            // rows 11..15
  vals[6] = fmaxf(fmaxf(e[0], e[1]), glt5 ? e[2] : -INFINITY);  // rows [0,21)
  vals[7] = fmaxf(fmaxf(e[2], e[3]), gge3 ? e[1] : -INFINITY);  // rows [11,32)

  // g-bit allreduce (bits 8,16,32): every lane gets its chunk's 8 values.
#pragma unroll
  for (int off = 8; off <= 32; off <<= 1) {
#pragma unroll
    for (int i = 0; i < 8; ++i)
      vals[i] = fmaxf(vals[i], __shfl_xor(vals[i], off, 64));
  }

  // Per-chunk row-band composites.
  const float M2a = fmaxf(fmaxf(vals[0], vals[1]), vals[4]);  // rows [0,21)
  const float M2b = fmaxf(vals[5], fmaxf(vals[2], vals[3]));  // rows [11,32)
  const float M3a = fmaxf(vals[0], vals[1]);                  // rows [0,16)
  const float M3b = fmaxf(vals[1], vals[2]);                  // rows [8,24)
  const float M3c = fmaxf(vals[2], vals[3]);                  // rows [16,32)
  const float E1 = vals[6], E2 = vals[7];

  // Scale-2 regions: masked full butterflies over c bits.
  float a1 = (c <= 4) ? M2a : (c5 ? E1 : -INFINITY);  // cols [0,21)
  float a2 = (c >= 3) ? M2a : (c2 ? E1 : -INFINITY);  // cols [11,32)
  float a3 = (c <= 4) ? M2b : (c5 ? E2 : -INFINITY);
  float a4 = (c >= 3) ? M2b : (c2 ? E2 : -INFINITY);
#pragma unroll
  for (int off = 1; off <= 4; off <<= 1) {
    a1 = fmaxf(a1, __shfl_xor(a1, off, 64));
    a2 = fmaxf(a2, __shfl_xor(a2, off, 64));
    a3 = fmaxf(a3, __shfl_xor(a3, off, 64));
    a4 = fmaxf(a4, __shfl_xor(a4, off, 64));
  }

  // Scale-3: pair (xor1) -> quad (xor2) + mid (xor6: pair23<->pair45).
  const float pA = fmaxf(M3a, __shfl_xor(M3a, 1, 64));
  const float pB = fmaxf(M3b, __shfl_xor(M3b, 1, 64));
  const float pC = fmaxf(M3c, __shfl_xor(M3c, 1, 64));
  const float qA = fmaxf(pA, __shfl_xor(pA, 2, 64));
  const float qB = fmaxf(pB, __shfl_xor(pB, 2, 64));
  const float qC = fmaxf(pC, __shfl_xor(pC, 2, 64));
  const float mA = fmaxf(pA, __shfl_xor(pA, 6, 64));  // valid lanes c=2..5
  const float mB = fmaxf(pB, __shfl_xor(pB, 6, 64));
  const float mC = fmaxf(pC, __shfl_xor(pC, 6, 64));

  // Global region: max over both quads of (rows[0,16) U rows[16,32)).
  const float t0 = fmaxf(qA, qC);
  const float r0 = fmaxf(t0, __shfl_xor(t0, 4, 64));

  // Gather values not locally present at their destination lane.
  const float b5 = __shfl(qA, 0, 64);   // M3a quad0 for lane 5
  const float b6 = __shfl(mA, 2, 64);   // M3a mid   for lane 6
  const float b9 = __shfl(mB, 2, 64);   // M3b mid   for lane 9
  const float b10 = __shfl(qB, 4, 64);  // M3b quad1 for lane 10

  // Destination lane l holds region r_l:
  //  0:r0  1..4:a1..a4  5:3a-q0  6:3a-mid  7:3a-q1(c7 local)
  //  8:3b-q0(c0 local)  9:3b-mid  10:3b-q1  11:3c-q0(c3)  12:3c-mid(c4)
  //  13:3c-q1(c5)
  float outv = r0;
  outv = (lane == 1) ? a1 : outv;
  outv = (lane == 2) ? a2 : outv;
  outv = (lane == 3) ? a3 : outv;
  outv = (lane == 4) ? a4 : outv;
  outv = (lane == 5) ? b5 : outv;
  outv = (lane == 6) ? b6 : outv;
  outv = (lane == 7) ? qA : outv;
  outv = (lane == 8) ? qB : outv;
  outv = (lane == 9) ? b9 : outv;
  outv = (lane == 10) ? b10 : outv;
  outv = (lane == 11) ? qC : outv;
  outv = (lane == 12) ? mC : outv;
  outv = (lane == 13) ? qC : outv;

  if (lane < 14) rm[(size_t)p * 16 + lane] = outv;

  // Per-block SS partial (sum over this block's 4 planes), plain store.
  __shared__ float red[4][16];
  if (lane < 14) red[wv][lane] = outv * outv;
  __syncthreads();
  if (wv == 0 && lane < 14)
    sspart[blockIdx.x * 16 + lane] =
        red[0][lane] + red[1][lane] + red[2][lane] + red[3][lane];
}

// K2: 256 blocks (b = bid>>3, slice = bid&7). Each block redundantly reduces
// its batch's 512 SS partials (32KB, LLC-hot) -> ninv[14] in LDS -> apply.
__global__ __launch_bounds__(256) void k2_apply(
    const float* __restrict__ rm, const float* __restrict__ sspart,
    float* __restrict__ out) {
  const int bid = blockIdx.x;
  const int tid = threadIdx.x;
  const int lane = tid & 63, wv = tid >> 6;
  const int b = bid >> 3;

  // Thread t sums partial entries (b*512 + 2t) and (b*512 + 2t + 1).
  const float4* e =
      reinterpret_cast<const float4*>(sspart + ((size_t)b * 512 + 2 * tid) * 16);
  const float4 u0 = e[0], u1 = e[1], u2 = e[2], u3 = e[3];
  const float4 w0 = e[4], w1 = e[5], w2 = e[6], w3 = e[7];
  float ss[14] = {u0.x + w0.x, u0.y + w0.y, u0.z + w0.z, u0.w + w0.w,
                  u1.x + w1.x, u1.y + w1.y, u1.z + w1.z, u1.w + w1.w,
                  u2.x + w2.x, u2.y + w2.y, u2.z + w2.z, u2.w + w2.w,
                  u3.x + w3.x, u3.y + w3.y};

#pragma unroll
  for (int off = 32; off >= 1; off >>= 1) {
#pragma unroll
    for (int i = 0; i < 14; ++i) ss[i] += __shfl_xor(ss[i], off, 64);
  }

  __shared__ float red[4][14];
  __shared__ float ninv[14];
  if (lane == 0) {
#pragma unroll
    for (int i = 0; i < 14; ++i) red[wv][i] = ss[i];
  }
  __syncthreads();
  if (tid < 14) {
    const float s = red[0][tid] + red[1][tid] + red[2][tid] + red[3][tid];
    const float w = (tid == 0) ? 2.0f : 1.0f;  // global region == l=1 region
    ninv[tid] = w / (sqrtf(s) + EPSF);
  }
  __syncthreads();

  const int p = b * 2048 + (bid & 7) * 256 + tid;
  const float4* q = reinterpret_cast<const float4*>(rm) + (size_t)p * 4;
  const float4 q0 = q[0], q1 = q[1], q2 = q[2], q3 = q[3];
  float o = ninv[0] * q0.x + ninv[1] * q0.y + ninv[2] * q0.z + ninv[3] * q0.w;
  o += ninv[4] * q1.x + ninv[5] * q1.y + ninv[6] * q1.z + ninv[7] * q1.w;
  o += ninv[8] * q2.x + ninv[9] * q2.y + ninv[10] * q2.z + ninv[11] * q2.w;
  o += ninv[12] * q3.x + ninv[13] * q3.y;
  out[p] = o;
}

extern "C" void kernel_launch(void* const* d_in, const int* in_sizes, int n_in,
                              void* d_out, int out_size, void* d_ws, size_t ws_size,
                              hipStream_t stream) {
  const float* x = (const float*)d_in[0];
  float* out = (float*)d_out;

  const size_t RM_BYTES = (size_t)65536 * 16 * 4;  // 4.19 MB
  float* rm = (float*)d_ws;
  float* sspart = (float*)((char*)d_ws + RM_BYTES);  // 16384*16 floats = 1 MB

  k1_regions<<<16384, 256, 0, stream>>>(x, rm, sspart);
  k2_apply<<<256, 256, 0, stream>>>(rm, sspart, out);
}